// Round 5
// baseline (1126.361 us; speedup 1.0000x reference)
//
#include <hip/hip_runtime.h>
#include <hip/hip_bf16.h>
#include <math.h>

#define B_ 4
#define C_ 512
#define N_ 4096

typedef float f32x4 __attribute__((ext_vector_type(4)));
typedef __bf16 bf16x8 __attribute__((ext_vector_type(8)));

#define AS1(p) ((const __attribute__((address_space(1))) unsigned int*)(p))
#define AS3(p) ((__attribute__((address_space(3))) unsigned int*)(p))

__device__ __forceinline__ unsigned short f2bf(float x){
    return __builtin_bit_cast(unsigned short, (__bf16)x);
}
__device__ __forceinline__ float bf2f(unsigned short b){
    unsigned u = ((unsigned)b)<<16;
    return __builtin_bit_cast(float, u);
}
__device__ __forceinline__ f32x4 mfma16(bf16x8 a, bf16x8 b, f32x4 c){
    return __builtin_amdgcn_mfma_f32_16x16x32_bf16(a, b, c, 0, 0, 0);
}

// ---------------- weight fp32 -> bf16 hi/lo split ----------------
__global__ void split_w(const float* __restrict__ src, unsigned short* __restrict__ hi,
                        unsigned short* __restrict__ lo){
    const int i = (blockIdx.x*256 + threadIdx.x)*4;
    f32x4 v = *(const f32x4*)(src + i);
    ushort4 h, l;
    unsigned short t0=f2bf(v[0]); h.x=t0; l.x=f2bf(v[0]-bf2f(t0));
    unsigned short t1=f2bf(v[1]); h.y=t1; l.y=f2bf(v[1]-bf2f(t1));
    unsigned short t2=f2bf(v[2]); h.z=t2; l.z=f2bf(v[2]-bf2f(t2));
    unsigned short t3=f2bf(v[3]); h.w=t3; l.w=f2bf(v[3]-bf2f(t3));
    *(ushort4*)(hi + i) = h;
    *(ushort4*)(lo + i) = l;
}

// ---------------- GroupNorm: partial sums ----------------
__global__ void gn_part(const float* __restrict__ x, float2* __restrict__ part){
    const int bg = blockIdx.y, blk = blockIdx.x, t = threadIdx.x;
    const float* base = x + (size_t)bg*(256*4096) + (size_t)blk*16384;
    float s = 0.f, q = 0.f;
    for (int i=0;i<16;i++){
        f32x4 v = *(const f32x4*)(base + i*1024 + t*4);
        s += v[0]+v[1]+v[2]+v[3];
        q += v[0]*v[0]+v[1]*v[1]+v[2]*v[2]+v[3]*v[3];
    }
    #pragma unroll
    for (int o=32;o>0;o>>=1){ s += __shfl_down(s, o); q += __shfl_down(q, o); }
    __shared__ float as[4], aq[4];
    if ((t&63)==0){ as[t>>6]=s; aq[t>>6]=q; }
    __syncthreads();
    if (t==0)
        part[bg*64 + blk] = make_float2(as[0]+as[1]+as[2]+as[3], aq[0]+aq[1]+aq[2]+aq[3]);
}

__global__ void gn_fin(const float2* __restrict__ part, float2* __restrict__ stats){
    const int bg = blockIdx.x, t = threadIdx.x;
    float2 p = part[bg*64 + t];
    float s = p.x, q = p.y;
    #pragma unroll
    for (int o=32;o>0;o>>=1){ s += __shfl_down(s,o); q += __shfl_down(q,o); }
    if (t==0){
        const float inv = 1.0f/(256.f*4096.f);
        float mu = s*inv;
        float var = q*inv - mu*mu;
        stats[bg] = make_float2(mu, rsqrtf(var + 1e-6f));
    }
}

// ---- GN apply + transpose + hi/lo split: x[B][C][N] -> hT[B][N][C] (bf16 hi,lo) ----
__global__ void gn_apply(const float* __restrict__ x, const float* __restrict__ gw,
                         const float* __restrict__ gb, const float2* __restrict__ stats,
                         unsigned short* __restrict__ hTh, unsigned short* __restrict__ hTl)
{
    const int b = blockIdx.z, c0 = blockIdx.y*32, n0 = blockIdx.x*32;
    const int t = threadIdx.x;
    __shared__ float tile[32][37];
    {
        const int cl = t>>3, nl = (t&7)*4;
        const int c = c0 + cl;
        const float2 st = stats[b*2 + (c>>8)];
        const float wv = gw[c], bvv = gb[c];
        const f32x4 v = *(const f32x4*)(x + ((size_t)b*C_ + c)*N_ + n0 + nl);
        #pragma unroll
        for (int i=0;i<4;i++) tile[cl][nl+i] = (v[i] - st.x)*st.y*wv + bvv;
    }
    __syncthreads();
    {
        const int nl = t>>3, cl = (t&7)*4;
        const int n = n0 + nl;
        float f0 = tile[cl+0][nl], f1 = tile[cl+1][nl], f2 = tile[cl+2][nl], f3 = tile[cl+3][nl];
        unsigned short h0=f2bf(f0), h1=f2bf(f1), h2=f2bf(f2), h3=f2bf(f3);
        ushort4 hh, ll;
        hh.x=h0; hh.y=h1; hh.z=h2; hh.w=h3;
        ll.x=f2bf(f0-bf2f(h0)); ll.y=f2bf(f1-bf2f(h1));
        ll.z=f2bf(f2-bf2f(h2)); ll.w=f2bf(f3-bf2f(h3));
        size_t o = ((size_t)b*N_ + n)*C_ + c0 + cl;
        *(ushort4*)(hTh + o) = hh;
        *(ushort4*)(hTl + o) = ll;
    }
}

// ---------------- conv GEMM: out[o,n] = sum_c W[o,c]*S[c,n] + bias[o] ----------------
template<int PROD, int MODE>
__global__ __launch_bounds__(256, 2) void conv_gemm(
    const unsigned short* __restrict__ Wh, const unsigned short* __restrict__ Wl,
    const unsigned short* __restrict__ Sh, const unsigned short* __restrict__ Sl,
    const float* __restrict__ bias,
    unsigned short* __restrict__ outHi, unsigned short* __restrict__ outLo,
    float* __restrict__ outF, const float* __restrict__ resid)
{
    const int b = blockIdx.z, o0 = blockIdx.y*128, n0 = blockIdx.x*128;
    const int t = threadIdx.x, w = t>>6, l = t&63, lr = l&15, lg = l>>4;
    const int ro = (w>>1)*64, co = (w&1)*64;
    __shared__ unsigned short Ah[128][40];
    __shared__ unsigned short Al[128][40];
    __shared__ unsigned short Bh[128][40];
    __shared__ unsigned short Bl[128][40];
    f32x4 acc[4][4];
    #pragma unroll
    for (int i=0;i<4;i++)
        #pragma unroll
        for (int j=0;j<4;j++) acc[i][j] = (f32x4){0.f,0.f,0.f,0.f};

    const size_t srcB = (size_t)b*N_*C_;
    for (int ks=0; ks<16; ks++){
        const int c0 = ks*32;
        #pragma unroll
        for (int i=0;i<2;i++){
            int u = t + i*256;
            int row = u>>2, sch = (u&3)*8;
            *(bf16x8*)&Ah[row][sch] = *(const bf16x8*)(Wh + (size_t)(o0+row)*C_ + c0 + sch);
            *(bf16x8*)&Bh[row][sch] = *(const bf16x8*)(Sh + srcB + (size_t)(n0+row)*C_ + c0 + sch);
            if constexpr (PROD==3){
                *(bf16x8*)&Al[row][sch] = *(const bf16x8*)(Wl + (size_t)(o0+row)*C_ + c0 + sch);
                *(bf16x8*)&Bl[row][sch] = *(const bf16x8*)(Sl + srcB + (size_t)(n0+row)*C_ + c0 + sch);
            }
        }
        __syncthreads();
        bf16x8 af[4], bfv[4], afl[4], bfl[4];
        #pragma unroll
        for (int i=0;i<4;i++){
            af[i]  = *(const bf16x8*)&Ah[ro + i*16 + lr][lg*8];
            bfv[i] = *(const bf16x8*)&Bh[co + i*16 + lr][lg*8];
            if constexpr (PROD==3){
                afl[i] = *(const bf16x8*)&Al[ro + i*16 + lr][lg*8];
                bfl[i] = *(const bf16x8*)&Bl[co + i*16 + lr][lg*8];
            }
        }
        #pragma unroll
        for (int i=0;i<4;i++)
            #pragma unroll
            for (int j=0;j<4;j++){
                acc[i][j] = mfma16(af[i], bfv[j], acc[i][j]);
                if constexpr (PROD==3){
                    acc[i][j] = mfma16(af[i],  bfl[j], acc[i][j]);
                    acc[i][j] = mfma16(afl[i], bfv[j], acc[i][j]);
                }
            }
        __syncthreads();
    }
    #pragma unroll
    for (int i=0;i<4;i++){
        const int ob = o0 + ro + i*16 + lg*4;
        #pragma unroll
        for (int j=0;j<4;j++){
            const int n = n0 + co + j*16 + lr;
            f32x4 v = acc[i][j];
            if constexpr (MODE==0){
                float v0 = v[0] + bias[ob+0]; unsigned short h0 = f2bf(v0);
                float v1 = v[1] + bias[ob+1]; unsigned short h1 = f2bf(v1);
                float v2 = v[2] + bias[ob+2]; unsigned short h2 = f2bf(v2);
                float v3 = v[3] + bias[ob+3]; unsigned short h3 = f2bf(v3);
                ushort4 hh, ll;
                hh.x=h0; hh.y=h1; hh.z=h2; hh.w=h3;
                ll.x=f2bf(v0-bf2f(h0)); ll.y=f2bf(v1-bf2f(h1));
                ll.z=f2bf(v2-bf2f(h2)); ll.w=f2bf(v3-bf2f(h3));
                *(ushort4*)(outHi + srcB + (size_t)n*C_ + ob) = hh;
                *(ushort4*)(outLo + srcB + (size_t)n*C_ + ob) = ll;
            } else if constexpr (MODE==1){
                #pragma unroll
                for (int r=0;r<4;r++)
                    outHi[((size_t)b*C_ + ob + r)*N_ + n] = f2bf(v[r] + bias[ob+r]);
            } else {
                #pragma unroll
                for (int r=0;r<4;r++){
                    size_t idx = ((size_t)b*C_ + ob + r)*N_ + n;
                    outF[idx] = resid[idx] + v[r] + bias[ob+r];
                }
            }
        }
    }
}

// ------- flash attention v5: single-phase 3-stage software pipeline -------
// Per iteration t (one barrier):
//   stage K(t+2) DMA | QK(t+1) -> ds_add Sb[(t+1)&1] | softmax(t) reads+zeroes
//   Sb[t&1] -> Pb[t&1] | PV(t-1) from Pb/vf | loadV(t) -> vf
//   then s_waitcnt vmcnt(4) lgkmcnt(0); s_barrier   (V loads fly across barrier)
__global__ __launch_bounds__(512, 2) void attn_flash5(
    const unsigned short* __restrict__ qTh, const unsigned short* __restrict__ qTl,
    const unsigned short* __restrict__ kTh, const unsigned short* __restrict__ kTl,
    const unsigned short* __restrict__ vB,  unsigned short* __restrict__ aoT)
{
    const int id = blockIdx.x;
    const int xcd = id & 7, slot = id >> 3;
    const int b = xcd >> 1;
    const int n0 = ((xcd & 1)*32 + slot)*64;
    const int t = threadIdx.x, w = t>>6, l = t&63, lr = l&15, lg = l>>4;
    const int fm2 = w>>2, fn = (w>>1)&1, ch = w&1;
    const int cw = w*64;

    __shared__ unsigned short khA[32*512];
    __shared__ unsigned short klA[32*512];
    __shared__ unsigned short khB[32*512];
    __shared__ unsigned short klB[32*512];
    __shared__ float Sb[2][64][36];                  // row-XOR swizzled, ds_add target
    __shared__ __align__(16) unsigned short Pb[2][64*32];  // rotated-slot layout
    __shared__ float rowM[64], rowS[64], rowF[2][64];

    // q fragments: 2 row-frags (fm2*32 + f*16), c-half ch, hi+lo
    bf16x8 qh[2][8], ql[2][8];
    #pragma unroll
    for (int f=0; f<2; f++){
        const size_t qr = ((size_t)b*N_ + n0 + fm2*32 + f*16 + lr)*C_ + ch*256;
        #pragma unroll
        for (int kc=0; kc<8; kc++){
            qh[f][kc] = *(const bf16x8*)(qTh + qr + kc*32 + lg*8);
            ql[f][kc] = *(const bf16x8*)(qTl + qr + kc*32 + lg*8);
        }
    }
    f32x4 accO[4][4];
    #pragma unroll
    for (int i=0;i<4;i++)
        #pragma unroll
        for (int j=0;j<4;j++) accO[i][j] = (f32x4){0.f,0.f,0.f,0.f};

    for (int i = t; i < 2*64*36; i += 512) ((float*)Sb)[i] = 0.f;
    if (t < 64){ rowM[t] = -INFINITY; rowS[t] = 0.f; }

    const size_t kBase = (size_t)b*N_*1024;   // bytes; C_*2 per row

    auto stage = [&](int mt, unsigned short* dh, unsigned short* dl){
        const size_t kb = kBase + (size_t)mt*32*1024;
        #pragma unroll
        for (int i=0;i<4;i++){
            const int d = i*8192 + t*16;
            const int row = i*8 + w;
            const int colb = (l*16) ^ ((row&7)<<4);
            const size_t g = kb + (size_t)row*1024 + colb;
            __builtin_amdgcn_global_load_lds(AS1((const char*)kTh + g), AS3((char*)dh + d), 16, 0, 0);
            __builtin_amdgcn_global_load_lds(AS1((const char*)kTl + g), AS3((char*)dl + d), 16, 0, 0);
        }
    };
    const float SC = 22.62741699796952f;

    stage(0, khA, klA);
    asm volatile("s_waitcnt vmcnt(0) lgkmcnt(0)" ::: "memory");
    __builtin_amdgcn_s_barrier();

    bf16x8 vf[4];

    for (int tt = -1; tt <= 128; ++tt){
        // ---- 1. stage K(tt+2) ----
        if (tt <= 125)
            stage(tt+2, ((tt+2)&1) ? khB : khA, ((tt+2)&1) ? klB : klA);

        // ---- 2. QK(tt+1): 48 MFMA -> ds_add partial S ----
        if (tt <= 126){
            const unsigned short* kh = ((tt+1)&1) ? khB : khA;
            const unsigned short* kl = ((tt+1)&1) ? klB : klA;
            f32x4 s0 = (f32x4){0.f,0.f,0.f,0.f}, s1 = s0;
            const int krow = fn*16 + lr;
            const int rbase = krow*1024;
            const int swz = (krow&7)<<4;
            __builtin_amdgcn_s_setprio(1);
            #pragma unroll
            for (int kc=0;kc<8;kc++){
                const int o = rbase + ((ch*512 + kc*64 + lg*16) ^ swz);
                bf16x8 kf  = *(const bf16x8*)((const char*)kh + o);
                bf16x8 kfl = *(const bf16x8*)((const char*)kl + o);
                s0 = mfma16(qh[0][kc], kf,  s0);
                s0 = mfma16(ql[0][kc], kf,  s0);
                s0 = mfma16(qh[0][kc], kfl, s0);
                s1 = mfma16(qh[1][kc], kf,  s1);
                s1 = mfma16(ql[1][kc], kf,  s1);
                s1 = mfma16(qh[1][kc], kfl, s1);
            }
            __builtin_amdgcn_s_setprio(0);
            float* sb = &Sb[(tt+1)&1][0][0];
            const int colL = fn*16 + lr;
            #pragma unroll
            for (int r=0;r<4;r++){
                const int row0 = fm2*32 + lg*4 + r;
                const int col0 = colL ^ ((((row0>>1)&7))<<2);
                atomicAdd(&sb[row0*36 + col0], s0[r]*SC);
                atomicAdd(&sb[(row0+16)*36 + col0], s1[r]*SC);
            }
        }

        // ---- 3. softmax(tt): read+zero Sb[tt&1], write Pb[tt&1] ----
        if (tt >= 0 && tt <= 127){
            float* sbuf = &Sb[tt&1][0][0];
            const int row = t>>3, j = t&7;
            float* srow = sbuf + row*36;
            const int cs = (4*j) ^ ((((row>>1)&7))<<2);
            f32x4 a4 = *(f32x4*)(srow + cs);
            *(f32x4*)(srow + cs) = (f32x4){0.f,0.f,0.f,0.f};
            float a0=a4[0], a1=a4[1], a2=a4[2], a3=a4[3];
            float mx = fmaxf(fmaxf(a0,a1), fmaxf(a2,a3));
            mx = fmaxf(mx, __shfl_xor(mx, 1, 8));
            mx = fmaxf(mx, __shfl_xor(mx, 2, 8));
            mx = fmaxf(mx, __shfl_xor(mx, 4, 8));
            const float mprev = rowM[row];
            const float mnew = fmaxf(mprev, mx);
            float p0 = __expf(a0 - mnew), p1 = __expf(a1 - mnew);
            float p2 = __expf(a2 - mnew), p3 = __expf(a3 - mnew);
            float ps = (p0+p1)+(p2+p3);
            ps += __shfl_xor(ps, 1, 8);
            ps += __shfl_xor(ps, 2, 8);
            ps += __shfl_xor(ps, 4, 8);
            ushort4 pk; pk.x=f2bf(p0); pk.y=f2bf(p1); pk.z=f2bf(p2); pk.w=f2bf(p3);
            char* pw = (char*)&Pb[tt&1][0] + row*64 + ((((j>>1) + (row>>1)) & 3)<<4) + ((j&1)<<3);
            *(ushort4*)pw = pk;
            if (j==0){
                float f = __expf(mprev - mnew);
                rowF[tt&1][row] = f;
                rowS[row] = rowS[row]*f + ps;
                rowM[row] = mnew;
            }
        }

        // ---- 4. PV(tt-1): rescale (gated) + 16 MFMA ----
        if (tt >= 1){
            const float* rf = rowF[(tt-1)&1];
            float frv[4][4]; bool need = false;
            #pragma unroll
            for (int am=0;am<4;am++)
                #pragma unroll
                for (int r=0;r<4;r++){
                    frv[am][r] = rf[am*16 + lg*4 + r];
                    need |= (frv[am][r] != 1.0f);
                }
            if (__any(need)){
                #pragma unroll
                for (int am=0;am<4;am++)
                    #pragma unroll
                    for (int ac=0;ac<4;ac++)
                        #pragma unroll
                        for (int r=0;r<4;r++) accO[am][ac][r] *= frv[am][r];
            }
            const char* pbuf = (const char*)&Pb[(tt-1)&1][0];
            bf16x8 pa[4];
            #pragma unroll
            for (int am=0;am<4;am++){
                const int prow = am*16 + lr;
                pa[am] = *(const bf16x8*)(pbuf + prow*64 + (((lg + (prow>>1)) & 3)<<4));
            }
            __builtin_amdgcn_s_setprio(1);
            #pragma unroll
            for (int ac=0;ac<4;ac++)
                #pragma unroll
                for (int am=0;am<4;am++)
                    accO[am][ac] = mfma16(pa[am], vf[ac], accO[am][ac]);
            __builtin_amdgcn_s_setprio(0);
        }

        // ---- 5. loadV(tt) -> vf (after PV consumed old vf) ----
        if (tt >= 0 && tt <= 127){
            const size_t vcol = (size_t)tt*32 + lg*8;
            #pragma unroll
            for (int ac=0;ac<4;ac++)
                vf[ac] = *(const bf16x8*)(vB + ((size_t)b*C_ + cw + ac*16 + lr)*N_ + vcol);
        }

        // ---- 6. counted drain + barrier ----
        if (tt >= 0 && tt <= 127)
            asm volatile("s_waitcnt vmcnt(4) lgkmcnt(0)" ::: "memory");
        else
            asm volatile("s_waitcnt vmcnt(0) lgkmcnt(0)" ::: "memory");
        __builtin_amdgcn_s_barrier();
    }

    // ---- normalize + write aoT[B][N][C] ----
    #pragma unroll
    for (int am=0;am<4;am++)
        #pragma unroll
        for (int r=0;r<4;r++){
            const int n = am*16 + lg*4 + r;
            const float inv = 1.0f / rowS[n];
            #pragma unroll
            for (int ac=0;ac<4;ac++)
                aoT[((size_t)b*N_ + n0 + n)*C_ + cw + ac*16 + lr] = f2bf(accO[am][ac][r]*inv);
        }
}

extern "C" void kernel_launch(void* const* d_in, const int* in_sizes, int n_in,
                              void* d_out, int out_size, void* d_ws, size_t ws_size,
                              hipStream_t stream)
{
    const float* x   = (const float*)d_in[0];
    const float* gnw = (const float*)d_in[1];
    const float* gnb = (const float*)d_in[2];
    const float* wq  = (const float*)d_in[3];
    const float* bq  = (const float*)d_in[4];
    const float* wk  = (const float*)d_in[5];
    const float* bk  = (const float*)d_in[6];
    const float* wv  = (const float*)d_in[7];
    const float* bv  = (const float*)d_in[8];
    const float* wp  = (const float*)d_in[9];
    const float* bp  = (const float*)d_in[10];
    float* out = (float*)d_out;

    char* ws = (char*)d_ws;
    size_t off = 0;
    auto alloc = [&](size_t bytes)->char*{
        char* p = ws + off; off += (bytes + 255) & ~(size_t)255; return p;
    };
    const size_t WB = (size_t)C_*C_*2;
    const size_t TB = (size_t)B_*N_*C_*2;
    unsigned short* wqh = (unsigned short*)alloc(WB);
    unsigned short* wql = (unsigned short*)alloc(WB);
    unsigned short* wkh = (unsigned short*)alloc(WB);
    unsigned short* wkl = (unsigned short*)alloc(WB);
    unsigned short* wvh = (unsigned short*)alloc(WB);
    unsigned short* wvl = (unsigned short*)alloc(WB);
    unsigned short* wph = (unsigned short*)alloc(WB);
    unsigned short* wpl = (unsigned short*)alloc(WB);
    unsigned short* hTh = (unsigned short*)alloc(TB);
    unsigned short* hTl = (unsigned short*)alloc(TB);
    unsigned short* qTh = (unsigned short*)alloc(TB);
    unsigned short* qTl = (unsigned short*)alloc(TB);
    unsigned short* kTh = (unsigned short*)alloc(TB);
    unsigned short* kTl = (unsigned short*)alloc(TB);
    unsigned short* vb  = (unsigned short*)alloc(TB);
    unsigned short* ao  = (unsigned short*)alloc(TB);
    float2* part  = (float2*)alloc(8*64*sizeof(float2));
    float2* stats = (float2*)alloc(8*sizeof(float2));

    split_w<<<256, 256, 0, stream>>>(wq, wqh, wql);
    split_w<<<256, 256, 0, stream>>>(wk, wkh, wkl);
    split_w<<<256, 256, 0, stream>>>(wv, wvh, wvl);
    split_w<<<256, 256, 0, stream>>>(wp, wph, wpl);
    gn_part<<<dim3(64, 8), 256, 0, stream>>>(x, part);
    gn_fin<<<8, 64, 0, stream>>>(part, stats);
    gn_apply<<<dim3(128, 16, B_), 256, 0, stream>>>(x, gnw, gnb, stats, hTh, hTl);
    conv_gemm<3,0><<<dim3(32,4,B_), 256, 0, stream>>>(wqh,wql,hTh,hTl,bq, qTh,qTl,nullptr,nullptr);
    conv_gemm<3,0><<<dim3(32,4,B_), 256, 0, stream>>>(wkh,wkl,hTh,hTl,bk, kTh,kTl,nullptr,nullptr);
    conv_gemm<1,1><<<dim3(32,4,B_), 256, 0, stream>>>(wvh,wvl,hTh,hTl,bv, vb,nullptr,nullptr,nullptr);
    attn_flash5<<<dim3(256), 512, 0, stream>>>(qTh,qTl,kTh,kTl,vb,ao);
    conv_gemm<1,2><<<dim3(32,4,B_), 256, 0, stream>>>(wph,wpl,ao,nullptr,bp, nullptr,nullptr,out,x);
}

// Round 6
// 533.500 us; speedup vs baseline: 2.1113x; 2.1113x over previous
//
#include <hip/hip_runtime.h>
#include <hip/hip_bf16.h>
#include <math.h>

#define B_ 4
#define C_ 512
#define N_ 4096

typedef float f32x4 __attribute__((ext_vector_type(4)));
typedef __bf16 bf16x8 __attribute__((ext_vector_type(8)));

#define AS1(p) ((const __attribute__((address_space(1))) unsigned int*)(p))
#define AS3(p) ((__attribute__((address_space(3))) unsigned int*)(p))

__device__ __forceinline__ unsigned short f2bf(float x){
    return __builtin_bit_cast(unsigned short, (__bf16)x);
}
__device__ __forceinline__ float bf2f(unsigned short b){
    unsigned u = ((unsigned)b)<<16;
    return __builtin_bit_cast(float, u);
}
__device__ __forceinline__ f32x4 mfma16(bf16x8 a, bf16x8 b, f32x4 c){
    return __builtin_amdgcn_mfma_f32_16x16x32_bf16(a, b, c, 0, 0, 0);
}

// ---------------- weight fp32 -> bf16 hi/lo split ----------------
__global__ void split_w(const float* __restrict__ src, unsigned short* __restrict__ hi,
                        unsigned short* __restrict__ lo){
    const int i = (blockIdx.x*256 + threadIdx.x)*4;
    f32x4 v = *(const f32x4*)(src + i);
    ushort4 h, l;
    unsigned short t0=f2bf(v[0]); h.x=t0; l.x=f2bf(v[0]-bf2f(t0));
    unsigned short t1=f2bf(v[1]); h.y=t1; l.y=f2bf(v[1]-bf2f(t1));
    unsigned short t2=f2bf(v[2]); h.z=t2; l.z=f2bf(v[2]-bf2f(t2));
    unsigned short t3=f2bf(v[3]); h.w=t3; l.w=f2bf(v[3]-bf2f(t3));
    *(ushort4*)(hi + i) = h;
    *(ushort4*)(lo + i) = l;
}

// ---------------- GroupNorm: partial sums ----------------
__global__ void gn_part(const float* __restrict__ x, float2* __restrict__ part){
    const int bg = blockIdx.y, blk = blockIdx.x, t = threadIdx.x;
    const float* base = x + (size_t)bg*(256*4096) + (size_t)blk*16384;
    float s = 0.f, q = 0.f;
    for (int i=0;i<16;i++){
        f32x4 v = *(const f32x4*)(base + i*1024 + t*4);
        s += v[0]+v[1]+v[2]+v[3];
        q += v[0]*v[0]+v[1]*v[1]+v[2]*v[2]+v[3]*v[3];
    }
    #pragma unroll
    for (int o=32;o>0;o>>=1){ s += __shfl_down(s, o); q += __shfl_down(q, o); }
    __shared__ float as[4], aq[4];
    if ((t&63)==0){ as[t>>6]=s; aq[t>>6]=q; }
    __syncthreads();
    if (t==0)
        part[bg*64 + blk] = make_float2(as[0]+as[1]+as[2]+as[3], aq[0]+aq[1]+aq[2]+aq[3]);
}

__global__ void gn_fin(const float2* __restrict__ part, float2* __restrict__ stats){
    const int bg = blockIdx.x, t = threadIdx.x;
    float2 p = part[bg*64 + t];
    float s = p.x, q = p.y;
    #pragma unroll
    for (int o=32;o>0;o>>=1){ s += __shfl_down(s,o); q += __shfl_down(q,o); }
    if (t==0){
        const float inv = 1.0f/(256.f*4096.f);
        float mu = s*inv;
        float var = q*inv - mu*mu;
        stats[bg] = make_float2(mu, rsqrtf(var + 1e-6f));
    }
}

// ---- GN apply + transpose + hi/lo split: x[B][C][N] -> hT[B][N][C] (bf16 hi,lo) ----
__global__ void gn_apply(const float* __restrict__ x, const float* __restrict__ gw,
                         const float* __restrict__ gb, const float2* __restrict__ stats,
                         unsigned short* __restrict__ hTh, unsigned short* __restrict__ hTl)
{
    const int b = blockIdx.z, c0 = blockIdx.y*32, n0 = blockIdx.x*32;
    const int t = threadIdx.x;
    __shared__ float tile[32][37];
    {
        const int cl = t>>3, nl = (t&7)*4;
        const int c = c0 + cl;
        const float2 st = stats[b*2 + (c>>8)];
        const float wv = gw[c], bvv = gb[c];
        const f32x4 v = *(const f32x4*)(x + ((size_t)b*C_ + c)*N_ + n0 + nl);
        #pragma unroll
        for (int i=0;i<4;i++) tile[cl][nl+i] = (v[i] - st.x)*st.y*wv + bvv;
    }
    __syncthreads();
    {
        const int nl = t>>3, cl = (t&7)*4;
        const int n = n0 + nl;
        float f0 = tile[cl+0][nl], f1 = tile[cl+1][nl], f2 = tile[cl+2][nl], f3 = tile[cl+3][nl];
        unsigned short h0=f2bf(f0), h1=f2bf(f1), h2=f2bf(f2), h3=f2bf(f3);
        ushort4 hh, ll;
        hh.x=h0; hh.y=h1; hh.z=h2; hh.w=h3;
        ll.x=f2bf(f0-bf2f(h0)); ll.y=f2bf(f1-bf2f(h1));
        ll.z=f2bf(f2-bf2f(h2)); ll.w=f2bf(f3-bf2f(h3));
        size_t o = ((size_t)b*N_ + n)*C_ + c0 + cl;
        *(ushort4*)(hTh + o) = hh;
        *(ushort4*)(hTl + o) = ll;
    }
}

// ---------------- conv GEMM: out[o,n] = sum_c W[o,c]*S[c,n] + bias[o] ----------------
template<int PROD, int MODE>
__global__ __launch_bounds__(256, 2) void conv_gemm(
    const unsigned short* __restrict__ Wh, const unsigned short* __restrict__ Wl,
    const unsigned short* __restrict__ Sh, const unsigned short* __restrict__ Sl,
    const float* __restrict__ bias,
    unsigned short* __restrict__ outHi, unsigned short* __restrict__ outLo,
    float* __restrict__ outF, const float* __restrict__ resid)
{
    const int b = blockIdx.z, o0 = blockIdx.y*128, n0 = blockIdx.x*128;
    const int t = threadIdx.x, w = t>>6, l = t&63, lr = l&15, lg = l>>4;
    const int ro = (w>>1)*64, co = (w&1)*64;
    __shared__ unsigned short Ah[128][40];
    __shared__ unsigned short Al[128][40];
    __shared__ unsigned short Bh[128][40];
    __shared__ unsigned short Bl[128][40];
    f32x4 acc[4][4];
    #pragma unroll
    for (int i=0;i<4;i++)
        #pragma unroll
        for (int j=0;j<4;j++) acc[i][j] = (f32x4){0.f,0.f,0.f,0.f};

    const size_t srcB = (size_t)b*N_*C_;
    for (int ks=0; ks<16; ks++){
        const int c0 = ks*32;
        #pragma unroll
        for (int i=0;i<2;i++){
            int u = t + i*256;
            int row = u>>2, sch = (u&3)*8;
            *(bf16x8*)&Ah[row][sch] = *(const bf16x8*)(Wh + (size_t)(o0+row)*C_ + c0 + sch);
            *(bf16x8*)&Bh[row][sch] = *(const bf16x8*)(Sh + srcB + (size_t)(n0+row)*C_ + c0 + sch);
            if constexpr (PROD==3){
                *(bf16x8*)&Al[row][sch] = *(const bf16x8*)(Wl + (size_t)(o0+row)*C_ + c0 + sch);
                *(bf16x8*)&Bl[row][sch] = *(const bf16x8*)(Sl + srcB + (size_t)(n0+row)*C_ + c0 + sch);
            }
        }
        __syncthreads();
        bf16x8 af[4], bfv[4], afl[4], bfl[4];
        #pragma unroll
        for (int i=0;i<4;i++){
            af[i]  = *(const bf16x8*)&Ah[ro + i*16 + lr][lg*8];
            bfv[i] = *(const bf16x8*)&Bh[co + i*16 + lr][lg*8];
            if constexpr (PROD==3){
                afl[i] = *(const bf16x8*)&Al[ro + i*16 + lr][lg*8];
                bfl[i] = *(const bf16x8*)&Bl[co + i*16 + lr][lg*8];
            }
        }
        #pragma unroll
        for (int i=0;i<4;i++)
            #pragma unroll
            for (int j=0;j<4;j++){
                acc[i][j] = mfma16(af[i], bfv[j], acc[i][j]);
                if constexpr (PROD==3){
                    acc[i][j] = mfma16(af[i],  bfl[j], acc[i][j]);
                    acc[i][j] = mfma16(afl[i], bfv[j], acc[i][j]);
                }
            }
        __syncthreads();
    }
    #pragma unroll
    for (int i=0;i<4;i++){
        const int ob = o0 + ro + i*16 + lg*4;
        #pragma unroll
        for (int j=0;j<4;j++){
            const int n = n0 + co + j*16 + lr;
            f32x4 v = acc[i][j];
            if constexpr (MODE==0){
                float v0 = v[0] + bias[ob+0]; unsigned short h0 = f2bf(v0);
                float v1 = v[1] + bias[ob+1]; unsigned short h1 = f2bf(v1);
                float v2 = v[2] + bias[ob+2]; unsigned short h2 = f2bf(v2);
                float v3 = v[3] + bias[ob+3]; unsigned short h3 = f2bf(v3);
                ushort4 hh, ll;
                hh.x=h0; hh.y=h1; hh.z=h2; hh.w=h3;
                ll.x=f2bf(v0-bf2f(h0)); ll.y=f2bf(v1-bf2f(h1));
                ll.z=f2bf(v2-bf2f(h2)); ll.w=f2bf(v3-bf2f(h3));
                *(ushort4*)(outHi + srcB + (size_t)n*C_ + ob) = hh;
                *(ushort4*)(outLo + srcB + (size_t)n*C_ + ob) = ll;
            } else if constexpr (MODE==1){
                #pragma unroll
                for (int r=0;r<4;r++)
                    outHi[((size_t)b*C_ + ob + r)*N_ + n] = f2bf(v[r] + bias[ob+r]);
            } else {
                #pragma unroll
                for (int r=0;r<4;r++){
                    size_t idx = ((size_t)b*C_ + ob + r)*N_ + n;
                    outF[idx] = resid[idx] + v[r] + bias[ob+r];
                }
            }
        }
    }
}

// -------- flash attention v6: R4 skeleton, PV moved into phase1 ----------
// phase1(it): PV(it-1) [Pb/rowF parity it-1, vf regs]  ||  softmax(it)
//             -> vmcnt(0) lgkm(0) barrier  (certifies K DMA of tile it+1)
// phase2(it): stage K(it+2) DMA | loadV(it) | QK(it+1) -> Sb
//             -> lgkm(0) barrier (publishes Sb)
__global__ __launch_bounds__(512, 2) void attn_flash6(
    const unsigned short* __restrict__ qTh, const unsigned short* __restrict__ qTl,
    const unsigned short* __restrict__ kTh, const unsigned short* __restrict__ kTl,
    const unsigned short* __restrict__ vB,  unsigned short* __restrict__ aoT)
{
    const int id = blockIdx.x;
    const int xcd = id & 7, slot = id >> 3;
    const int b = xcd >> 1;
    const int n0 = ((xcd & 1)*32 + slot)*64;
    const int t = threadIdx.x, w = t>>6, l = t&63, lr = l&15, lg = l>>4;
    const int fm2 = w>>2, fn = (w>>1)&1, ch = w&1;
    const int cw = w*64;

    __shared__ unsigned short khA[32*512];
    __shared__ unsigned short klA[32*512];
    __shared__ unsigned short khB[32*512];
    __shared__ unsigned short klB[32*512];
    __shared__ float Sb[2][64][34];                         // stride 34: 2-way-free writes
    __shared__ __align__(16) unsigned short Pb[2][64][34];  // parity dbuf; b128 reads conflict-free
    __shared__ float rowM[64], rowS[64], rowF[2][64];

    // q fragments: 2 row-frags (fm2*32 + f*16), c-half ch, hi+lo
    bf16x8 qh[2][8], ql[2][8];
    #pragma unroll
    for (int f=0; f<2; f++){
        const size_t qr = ((size_t)b*N_ + n0 + fm2*32 + f*16 + lr)*C_ + ch*256;
        #pragma unroll
        for (int kc=0; kc<8; kc++){
            qh[f][kc] = *(const bf16x8*)(qTh + qr + kc*32 + lg*8);
            ql[f][kc] = *(const bf16x8*)(qTl + qr + kc*32 + lg*8);
        }
    }
    f32x4 accO[4][4];
    #pragma unroll
    for (int i=0;i<4;i++)
        #pragma unroll
        for (int j=0;j<4;j++) accO[i][j] = (f32x4){0.f,0.f,0.f,0.f};
    if (t < 64){ rowM[t] = -INFINITY; rowS[t] = 0.f; }

    const size_t kBase = (size_t)b*N_*1024;   // bytes; C_*2 per row

    auto stage = [&](int mt, unsigned short* dh, unsigned short* dl){
        const size_t kb = kBase + (size_t)mt*32*1024;
        #pragma unroll
        for (int i=0;i<4;i++){
            const int d = i*8192 + t*16;
            const int row = i*8 + w;
            const int colb = (l*16) ^ ((row&7)<<4);
            const size_t g = kb + (size_t)row*1024 + colb;
            __builtin_amdgcn_global_load_lds(AS1((const char*)kTh + g), AS3((char*)dh + d), 16, 0, 0);
            __builtin_amdgcn_global_load_lds(AS1((const char*)kTl + g), AS3((char*)dl + d), 16, 0, 0);
        }
    };
    auto loadV = [&](int mt, bf16x8* vf){
        const size_t vcol = (size_t)mt*32 + lg*8;
        #pragma unroll
        for (int ac=0;ac<4;ac++)
            vf[ac] = *(const bf16x8*)(vB + ((size_t)b*C_ + cw + ac*16 + lr)*N_ + vcol);
    };
    const float SC = 22.62741699796952f;
    auto qk_tile = [&](const unsigned short* kh, const unsigned short* kl){
        f32x4 s0 = (f32x4){0.f,0.f,0.f,0.f}, s1 = s0;
        const int krow = fn*16 + lr;
        const int rbase = krow*1024;
        const int swz = (krow&7)<<4;
        __builtin_amdgcn_s_setprio(1);
        #pragma unroll
        for (int kc=0;kc<8;kc++){
            const int o = rbase + ((ch*512 + kc*64 + lg*16) ^ swz);
            bf16x8 kf  = *(const bf16x8*)((const char*)kh + o);
            bf16x8 kfl = *(const bf16x8*)((const char*)kl + o);
            s0 = mfma16(qh[0][kc], kf,  s0);
            s0 = mfma16(ql[0][kc], kf,  s0);
            s0 = mfma16(qh[0][kc], kfl, s0);
            s1 = mfma16(qh[1][kc], kf,  s1);
            s1 = mfma16(ql[1][kc], kf,  s1);
            s1 = mfma16(qh[1][kc], kfl, s1);
        }
        __builtin_amdgcn_s_setprio(0);
        #pragma unroll
        for (int r=0;r<4;r++){
            Sb[ch][fm2*32 +      lg*4 + r][fn*16 + lr] = s0[r]*SC;
            Sb[ch][fm2*32 + 16 + lg*4 + r][fn*16 + lr] = s1[r]*SC;
        }
    };

    bf16x8 vf[4];

    // prologue: stage tiles 0,1; compute S(0)
    stage(0, khA, klA);
    stage(1, khB, klB);
    asm volatile("s_waitcnt vmcnt(8)" ::: "memory");   // tile0 landed; tile1 in flight
    __builtin_amdgcn_s_barrier();
    qk_tile(khA, klA);
    asm volatile("s_waitcnt lgkmcnt(0)" ::: "memory");
    __builtin_amdgcn_s_barrier();

    for (int it=0; it<128; ++it){
        // ================= phase1: PV(it-1) || softmax(it) =================
        if (it > 0){
            const int pp = (it-1)&1;
            float frv[4][4]; bool need = false;
            #pragma unroll
            for (int am=0;am<4;am++)
                #pragma unroll
                for (int r=0;r<4;r++){
                    frv[am][r] = rowF[pp][am*16 + lg*4 + r];
                    need |= (frv[am][r] != 1.0f);
                }
            if (__any(need)){
                #pragma unroll
                for (int am=0;am<4;am++)
                    #pragma unroll
                    for (int ac=0;ac<4;ac++)
                        #pragma unroll
                        for (int r=0;r<4;r++) accO[am][ac][r] *= frv[am][r];
            }
            __builtin_amdgcn_s_setprio(1);
            #pragma unroll
            for (int am=0;am<4;am++){
                bf16x8 pa = *(const bf16x8*)&Pb[pp][am*16 + lr][lg*8];
                #pragma unroll
                for (int ac=0;ac<4;ac++)
                    accO[am][ac] = mfma16(pa, vf[ac], accO[am][ac]);
            }
            __builtin_amdgcn_s_setprio(0);
        }
        {
            const int row = t>>3, j = t&7;
            const float* s0p = &Sb[0][row][j*4];
            const float* s1p = &Sb[1][row][j*4];
            float a0 = s0p[0] + s1p[0];
            float a1 = s0p[1] + s1p[1];
            float a2 = s0p[2] + s1p[2];
            float a3 = s0p[3] + s1p[3];
            float mx = fmaxf(fmaxf(a0,a1), fmaxf(a2,a3));
            mx = fmaxf(mx, __shfl_xor(mx, 1, 8));
            mx = fmaxf(mx, __shfl_xor(mx, 2, 8));
            mx = fmaxf(mx, __shfl_xor(mx, 4, 8));
            const float mprev = rowM[row];
            const float mnew = fmaxf(mprev, mx);
            float p0 = __expf(a0 - mnew), p1 = __expf(a1 - mnew);
            float p2 = __expf(a2 - mnew), p3 = __expf(a3 - mnew);
            float ps = (p0+p1)+(p2+p3);
            ps += __shfl_xor(ps, 1, 8);
            ps += __shfl_xor(ps, 2, 8);
            ps += __shfl_xor(ps, 4, 8);
            ushort4 pk; pk.x=f2bf(p0); pk.y=f2bf(p1); pk.z=f2bf(p2); pk.w=f2bf(p3);
            *(ushort4*)&Pb[it&1][row][j*4] = pk;
            if (j==0){
                float f = __expf(mprev - mnew);
                rowF[it&1][row] = f;
                rowS[row] = rowS[row]*f + ps;
                rowM[row] = mnew;
            }
        }
        asm volatile("s_waitcnt vmcnt(0) lgkmcnt(0)" ::: "memory");
        __builtin_amdgcn_s_barrier();

        // ================= phase2: stage(it+2) | loadV(it) | QK(it+1) ======
        if (it <= 125) stage(it+2, (it&1) ? khB : khA, (it&1) ? klB : klA);
        loadV(it, vf);
        if (it <= 126) qk_tile(((it+1)&1) ? khB : khA, ((it+1)&1) ? klB : klA);
        asm volatile("s_waitcnt lgkmcnt(0)" ::: "memory");
        __builtin_amdgcn_s_barrier();
    }

    // ---- epilogue: PV(127) ----
    {
        const int pp = 1;
        float frv[4][4]; bool need = false;
        #pragma unroll
        for (int am=0;am<4;am++)
            #pragma unroll
            for (int r=0;r<4;r++){
                frv[am][r] = rowF[pp][am*16 + lg*4 + r];
                need |= (frv[am][r] != 1.0f);
            }
        if (__any(need)){
            #pragma unroll
            for (int am=0;am<4;am++)
                #pragma unroll
                for (int ac=0;ac<4;ac++)
                    #pragma unroll
                    for (int r=0;r<4;r++) accO[am][ac][r] *= frv[am][r];
        }
        #pragma unroll
        for (int am=0;am<4;am++){
            bf16x8 pa = *(const bf16x8*)&Pb[pp][am*16 + lr][lg*8];
            #pragma unroll
            for (int ac=0;ac<4;ac++)
                accO[am][ac] = mfma16(pa, vf[ac], accO[am][ac]);
        }
    }

    // ---- normalize + write aoT[B][N][C] ----
    #pragma unroll
    for (int am=0;am<4;am++)
        #pragma unroll
        for (int r=0;r<4;r++){
            const int n = am*16 + lg*4 + r;
            const float inv = 1.0f / rowS[n];
            #pragma unroll
            for (int ac=0;ac<4;ac++)
                aoT[((size_t)b*N_ + n0 + n)*C_ + cw + ac*16 + lr] = f2bf(accO[am][ac][r]*inv);
        }
}

extern "C" void kernel_launch(void* const* d_in, const int* in_sizes, int n_in,
                              void* d_out, int out_size, void* d_ws, size_t ws_size,
                              hipStream_t stream)
{
    const float* x   = (const float*)d_in[0];
    const float* gnw = (const float*)d_in[1];
    const float* gnb = (const float*)d_in[2];
    const float* wq  = (const float*)d_in[3];
    const float* bq  = (const float*)d_in[4];
    const float* wk  = (const float*)d_in[5];
    const float* bk  = (const float*)d_in[6];
    const float* wv  = (const float*)d_in[7];
    const float* bv  = (const float*)d_in[8];
    const float* wp  = (const float*)d_in[9];
    const float* bp  = (const float*)d_in[10];
    float* out = (float*)d_out;

    char* ws = (char*)d_ws;
    size_t off = 0;
    auto alloc = [&](size_t bytes)->char*{
        char* p = ws + off; off += (bytes + 255) & ~(size_t)255; return p;
    };
    const size_t WB = (size_t)C_*C_*2;
    const size_t TB = (size_t)B_*N_*C_*2;
    unsigned short* wqh = (unsigned short*)alloc(WB);
    unsigned short* wql = (unsigned short*)alloc(WB);
    unsigned short* wkh = (unsigned short*)alloc(WB);
    unsigned short* wkl = (unsigned short*)alloc(WB);
    unsigned short* wvh = (unsigned short*)alloc(WB);
    unsigned short* wvl = (unsigned short*)alloc(WB);
    unsigned short* wph = (unsigned short*)alloc(WB);
    unsigned short* wpl = (unsigned short*)alloc(WB);
    unsigned short* hTh = (unsigned short*)alloc(TB);
    unsigned short* hTl = (unsigned short*)alloc(TB);
    unsigned short* qTh = (unsigned short*)alloc(TB);
    unsigned short* qTl = (unsigned short*)alloc(TB);
    unsigned short* kTh = (unsigned short*)alloc(TB);
    unsigned short* kTl = (unsigned short*)alloc(TB);
    unsigned short* vb  = (unsigned short*)alloc(TB);
    unsigned short* ao  = (unsigned short*)alloc(TB);
    float2* part  = (float2*)alloc(8*64*sizeof(float2));
    float2* stats = (float2*)alloc(8*sizeof(float2));

    split_w<<<256, 256, 0, stream>>>(wq, wqh, wql);
    split_w<<<256, 256, 0, stream>>>(wk, wkh, wkl);
    split_w<<<256, 256, 0, stream>>>(wv, wvh, wvl);
    split_w<<<256, 256, 0, stream>>>(wp, wph, wpl);
    gn_part<<<dim3(64, 8), 256, 0, stream>>>(x, part);
    gn_fin<<<8, 64, 0, stream>>>(part, stats);
    gn_apply<<<dim3(128, 16, B_), 256, 0, stream>>>(x, gnw, gnb, stats, hTh, hTl);
    conv_gemm<3,0><<<dim3(32,4,B_), 256, 0, stream>>>(wqh,wql,hTh,hTl,bq, qTh,qTl,nullptr,nullptr);
    conv_gemm<3,0><<<dim3(32,4,B_), 256, 0, stream>>>(wkh,wkl,hTh,hTl,bk, kTh,kTl,nullptr,nullptr);
    conv_gemm<1,1><<<dim3(32,4,B_), 256, 0, stream>>>(wvh,wvl,hTh,hTl,bv, vb,nullptr,nullptr,nullptr);
    attn_flash6<<<dim3(256), 512, 0, stream>>>(qTh,qTl,kTh,kTl,vb,ao);
    conv_gemm<1,2><<<dim3(32,4,B_), 256, 0, stream>>>(wph,wpl,ao,nullptr,bp, nullptr,nullptr,out,x);
}